// Round 10
// baseline (1224.953 us; speedup 1.0000x reference)
//
#include <hip/hip_runtime.h>
#include <math.h>

// ---------------------------------------------------------------------------
// Disentangler: 32 component-MLPs over sampled token rows + masked seg-pool.
// Round-10: m201-style 8-phase K-loop (4 phases/tile, 2 tiles/unrolled iter),
// 256x256 block / 8 waves of 128x64, per-tile LDS dbuf (128 KB), NO
// sched_barrier pinning, staging interleaved per phase (A glds p0, B fp32
// loads p0/p1, swizzled B b64-writes p2/p3 -> implicit counted vmcnt).
// Fused W-transpose (no prep kernels). Operands pre-swizzled bf16 (Ab, h).
// ---------------------------------------------------------------------------

typedef __attribute__((ext_vector_type(8))) short bf16x8;
typedef __attribute__((ext_vector_type(4))) short s16x4;
typedef __attribute__((ext_vector_type(4))) float f32x4;
typedef unsigned int u32;

constexpr int TT    = 16;
constexpr int TOKN  = 4096;
constexpr int DD    = 2048;
constexpr int HH    = 2048;
constexpr int CC    = 1024;
constexpr int LL    = 1000;
constexpr int NCOMP = 32;
constexpr int MP    = 1024;
constexpr int BMX = 256, BNX = 256;
constexpr int MTX  = MP / BMX;    // 4 m-tiles
constexpr int NT1X = HH / BNX;    // 8 n-tiles (gemm1)
constexpr int NT2X = CC / BNX;    // 4 n-tiles (gemm2)
constexpr int NT   = 2048 / 64;   // 32 K-tiles (K = 2048 both GEMMs)

__device__ __forceinline__ short f2bf(float f) {
  __bf16 h = (__bf16)f;
  return *reinterpret_cast<short*>(&h);
}
// Row swizzle (period 64): data-granule g of a 64-elem chunk lives at slot
// g ^ swz(row). Identical layout in Ab, h, and the LDS tiles.
__device__ __forceinline__ int swz(int row) {
  return (row & 7) ^ ((row >> 3) & 7);
}
__device__ __forceinline__ int sw(int row, int gran) {   // short offset
  return (row << 6) + ((gran ^ swz(row)) << 3);
}
__device__ __forceinline__ void gl_lds16(const void* g, void* l) {
  __builtin_amdgcn_global_load_lds(
      (const __attribute__((address_space(1))) u32*)g,
      (__attribute__((address_space(3))) u32*)l, 16, 0, 0);
}

// --------------------------- dedup ----------------------------------------
__global__ void dedup_kernel(const int* __restrict__ ridx,
                             unsigned* __restrict__ bitmap,
                             float* __restrict__ keepf) {
  int comp = blockIdx.x;
  for (int l = threadIdx.x; l < MP; l += 256) {
    float kv = 0.0f;
    if (l < LL) {
      int r = ridx[comp * LL + l];
      unsigned bit = 1u << (r & 31);
      unsigned old = atomicOr(&bitmap[(comp << 10) + (r >> 5)], bit);
      kv = (old & bit) ? 0.0f : 1.0f;
    }
    keepf[(comp << 10) + l] = kv;
  }
}

// --------------------------- gather: x rows -> pre-swizzled bf16 -----------
__global__ __launch_bounds__(256) void gather_kernel(
    const float* __restrict__ x, const int* __restrict__ ridx,
    short* __restrict__ Ab) {
  int bid = blockIdx.x;
  int comp = bid >> 7, rgrp = bid & 127;
  int t = threadIdx.x;
  int tr = t >> 5, tn = t & 31;
  int m = rgrp * 8 + tr;
  int mi = m < LL ? m : LL - 1;
  int r = ridx[comp * LL + mi];
  int tokoff = comp >= 16 ? TOKN / 2 : 0;
  const float* src = x + ((size_t)(r >> 11) * TOKN + (r & 2047) + tokoff) * DD;
  short* drow = Ab + ((size_t)(comp * MP + m)) * DD;
  int s_m = swz(m);
#pragma unroll
  for (int i = 0; i < 8; ++i) {
    int gi = tn + 32 * i;
    float4 f0 = *reinterpret_cast<const float4*>(src + gi * 8);
    float4 f1 = *reinterpret_cast<const float4*>(src + gi * 8 + 4);
    bf16x8 pk;
    pk[0]=f2bf(f0.x); pk[1]=f2bf(f0.y); pk[2]=f2bf(f0.z); pk[3]=f2bf(f0.w);
    pk[4]=f2bf(f1.x); pk[5]=f2bf(f1.y); pk[6]=f2bf(f1.z); pk[7]=f2bf(f1.w);
    int c = gi >> 3, g = gi & 7;
    *reinterpret_cast<bf16x8*>(&drow[c * 64 + ((g ^ s_m) << 3)]) = pk;
  }
}

// --------------------------- shared 8-phase K-loop -------------------------
// LDS (shorts): A[dbuf=t&1][16384] @0 (256x64), B[dbuf][16384] @32768.
// Tile t (4 phases): p0 {rdA q0 + rdB c0 | 4xglds A(t+1) + 4x bload B(t+1)}
//                    p1 {rdB c1 | 4x bload B(t+1)}
//                    p2 {rdA q1 | 4x b64 bwrite B(t+1) k-half0}
//                    p3 {       | 4x b64 bwrite B(t+1) k-half1}
// each phase: barrier, lgkm(0), setprio(1), 16 MFMA, setprio(0), barrier.
// bwrite's compiler-exact vmcnt waits transitively drain A(t+1) glds with
// >=2-phase issue distance; no explicit vmcnt, no sched_barrier.
template<int LDW>
__device__ __forceinline__ void kloop8(
    const short* __restrict__ aBase,   // bf16 pre-swizzled rows, stride 2048
    const float* __restrict__ wBase,   // fp32 W [k][LDW] at col offset nt*BNX
    short* sm, f32x4 (&acc)[8][4], int wr, int wc, int lr, int lg, int tid) {
  const short* aSrc0 = aBase + (size_t)(tid >> 3) * 2048 + (tid & 7) * 8;
  int ldsA0 = tid * 8;
  int tn = tid & 63, tkb = tid >> 6, bn0 = tn * 4;
  const float* wCol = wBase + bn0;

  float4 br[8];
  bf16x8 af[2][4], bj0[2][2], bj1[2][2];

  auto aglds = [&](int t) {            // 4 glds: A(t) 32 KB -> dbuf t&1
    short* l = sm + (t & 1) * 16384;
#pragma unroll
    for (int q = 0; q < 4; ++q)
      gl_lds16(aSrc0 + (size_t)q * 131072 + t * 64, l + ldsA0 + q * 4096);
  };
  auto bload4 = [&](int t, int h) {    // 4 float4: k rows tkb*8+h*4..+3
    const float* bb = wCol + (size_t)(t * 64 + tkb * 8 + h * 4) * LDW;
#pragma unroll
    for (int i = 0; i < 4; ++i)
      br[h * 4 + i] = *reinterpret_cast<const float4*>(bb + (size_t)i * LDW);
  };
  auto bwrite4 = [&](int t, int h) {   // 4 b64: cols bn0..+3, k-half h
    short* Bs = sm + 32768 + (t & 1) * 16384;
#pragma unroll
    for (int j = 0; j < 4; ++j) {
      s16x4 pk;
#pragma unroll
      for (int i = 0; i < 4; ++i) pk[i] = f2bf((&br[h * 4 + i].x)[j]);
      *reinterpret_cast<s16x4*>(&Bs[sw(bn0 + j, tkb) + h * 4]) = pk;
    }
  };
  auto rdA = [&](int d, int qr) {
#pragma unroll
    for (int kk = 0; kk < 2; ++kk)
#pragma unroll
      for (int i = 0; i < 4; ++i)
        af[kk][i] = *reinterpret_cast<const bf16x8*>(
            &sm[d * 16384 + sw(wr * 128 + qr * 64 + i * 16 + lr, kk * 4 + lg)]);
  };
  auto rdB = [&](int d, int qc, bf16x8 (&bj)[2][2]) {
#pragma unroll
    for (int kk = 0; kk < 2; ++kk)
#pragma unroll
      for (int j = 0; j < 2; ++j)
        bj[kk][j] = *reinterpret_cast<const bf16x8*>(
            &sm[32768 + d * 16384 + sw(wc * 64 + qc * 32 + j * 16 + lr, kk * 4 + lg)]);
  };
  auto mfma16 = [&](bf16x8 (&bj)[2][2], int I0, int J0) {
    __builtin_amdgcn_s_setprio(1);
#pragma unroll
    for (int kk = 0; kk < 2; ++kk)
#pragma unroll
      for (int i = 0; i < 4; ++i)
#pragma unroll
        for (int j = 0; j < 2; ++j)
          acc[I0 + i][J0 + j] = __builtin_amdgcn_mfma_f32_16x16x32_bf16(
              af[kk][i], bj[kk][j], acc[I0 + i][J0 + j], 0, 0, 0);
    __builtin_amdgcn_s_setprio(0);
  };

  auto tile = [&](int t, bool stg) {
    int d = t & 1;
    // ---- phase 0: quadrant (0,0)
    rdA(d, 0); rdB(d, 0, bj0);
    if (stg) { aglds(t + 1); bload4(t + 1, 0); }
    __builtin_amdgcn_s_barrier();
    asm volatile("s_waitcnt lgkmcnt(0)" ::: "memory");
    mfma16(bj0, 0, 0);
    __builtin_amdgcn_s_barrier();
    // ---- phase 1: quadrant (0,1)
    rdB(d, 1, bj1);
    if (stg) bload4(t + 1, 1);
    __builtin_amdgcn_s_barrier();
    asm volatile("s_waitcnt lgkmcnt(0)" ::: "memory");
    mfma16(bj1, 0, 2);
    __builtin_amdgcn_s_barrier();
    // ---- phase 2: quadrant (1,1)
    rdA(d, 1);
    if (stg) bwrite4(t + 1, 0);        // auto vmcnt: p0 loads (2-phase cover)
    __builtin_amdgcn_s_barrier();
    asm volatile("s_waitcnt lgkmcnt(0)" ::: "memory");
    mfma16(bj1, 4, 2);
    __builtin_amdgcn_s_barrier();
    // ---- phase 3: quadrant (1,0)
    if (stg) bwrite4(t + 1, 1);        // auto vmcnt: drains glds A(t+1) too
    __builtin_amdgcn_s_barrier();
    asm volatile("s_waitcnt lgkmcnt(0)" ::: "memory");
    mfma16(bj0, 4, 0);
    __builtin_amdgcn_s_barrier();
  };

  // prologue: A(0) glds + B(0) regs -> LDS, full drain, barrier
  aglds(0);
  bload4(0, 0); bload4(0, 1);
  bwrite4(0, 0); bwrite4(0, 1);
  asm volatile("s_waitcnt vmcnt(0) lgkmcnt(0)" ::: "memory");
  __builtin_amdgcn_s_barrier();

#pragma unroll 1
  for (int tp = 0; tp < NT / 2; ++tp) {
    tile(2 * tp, true);
    tile(2 * tp + 1, tp < NT / 2 - 1);
  }
  __builtin_amdgcn_s_barrier();
}

// --------------------------- GEMM1: h = gelu(x_sel @ W1 + b1) --------------
__global__ __launch_bounds__(512, 2) void gemm1_kernel(
    const float* __restrict__ nW1, const float* __restrict__ nb1,
    const float* __restrict__ eW1, const float* __restrict__ eb1,
    const short* __restrict__ Ab, short* __restrict__ hbuf) {
  __shared__ short smem[65536];   // 128 KB

  constexpr int NWG = NCOMP * MTX * NT1X;   // 1024
  constexpr int CPX = NWG / 8;
  int b0 = blockIdx.x;
  int lb = (b0 & 7) * CPX + (b0 >> 3);      // XCD-chunked (T1), bijective
  int comp = lb / (MTX * NT1X);
  int rem  = lb % (MTX * NT1X);
  int mt = rem / NT1X, nt = rem % NT1X;
  bool isEdge = comp >= 16;
  int k16 = isEdge ? comp - 16 : comp;
  const float* W1 = (isEdge ? eW1 : nW1) + (size_t)k16 * DD * HH;
  const float* b1 = (isEdge ? eb1 : nb1) + (size_t)k16 * HH;

  int tid = threadIdx.x, lane = tid & 63, wid = tid >> 6;
  int wr = wid >> 2, wc = wid & 3;          // 2M x 4N waves; wave 128x64
  int lr = lane & 15, lg = lane >> 4;

  f32x4 acc[8][4] = {};
  kloop8<HH>(Ab + ((size_t)(comp * MP + mt * BMX)) * DD,
             W1 + nt * BNX, smem, acc, wr, wc, lr, lg, tid);

  // epilogue: +b1, exact gelu; two 128-row phases bounce through LDS, then
  // coalesced PRE-SWIZZLED bf16 h store (so gemm2 can global_load_lds it)
  short* Cs = smem;                          // stride 264 shorts
  const float* b1p = b1 + nt * BNX;
#pragma unroll 1
  for (int p = 0; p < 2; ++p) {
    if (wr == p) {
#pragma unroll
      for (int i = 0; i < 8; ++i)
#pragma unroll
        for (int j = 0; j < 4; ++j) {
          int nl = wc * 64 + j * 16 + lr;
          float bias = b1p[nl];
#pragma unroll
          for (int rr = 0; rr < 4; ++rr) {
            int r = i * 16 + lg * 4 + rr;    // 0..127 within phase
            float v = acc[i][j][rr] + bias;
            float ge = 0.5f * v * (1.0f + erff(v * 0.70710678118654752f));
            Cs[r * 264 + nl] = f2bf(ge);
          }
        }
    }
    __syncthreads();
    short* hrow = hbuf + ((size_t)(comp * MP + mt * BMX + p * 128)) * HH;
#pragma unroll
    for (int q = 0; q < 8; ++q) {
      int f = q * 512 + tid;
      int r = f >> 5, g8 = f & 31;           // 32 8-short granules per row
      bf16x8 v = *reinterpret_cast<const bf16x8*>(&Cs[r * 264 + g8 * 8]);
      int dst = (nt * 4 + (g8 >> 3)) * 64 + (((g8 & 7) ^ swz(r)) << 3);
      *reinterpret_cast<bf16x8*>(&hrow[(size_t)r * HH + dst]) = v;
    }
    __syncthreads();
  }
}

// --------------------------- GEMM2: o = h @ W2 + b2, masked seg-reduce -----
__global__ __launch_bounds__(512, 2) void gemm2_kernel(
    const short* __restrict__ hbuf, const int* __restrict__ ridx,
    const float* __restrict__ nW2, const float* __restrict__ nb2,
    const float* __restrict__ eW2, const float* __restrict__ eb2,
    const float* __restrict__ keepf, float* __restrict__ partial) {
  __shared__ short smem[65536];

  constexpr int NWG = NCOMP * MTX * NT2X;   // 512
  constexpr int CPX = NWG / 8;
  int b0 = blockIdx.x;
  int lb = (b0 & 7) * CPX + (b0 >> 3);
  int comp = lb / (MTX * NT2X);
  int rem  = lb % (MTX * NT2X);
  int mt = rem / NT2X, nt = rem % NT2X;
  bool isEdge = comp >= 16;
  int k16 = isEdge ? comp - 16 : comp;
  const float* W2 = (isEdge ? eW2 : nW2) + (size_t)k16 * HH * CC;
  const float* b2 = (isEdge ? eb2 : nb2) + (size_t)k16 * CC;

  int tid = threadIdx.x, lane = tid & 63, wid = tid >> 6;
  int wr = wid >> 2, wc = wid & 3;
  int lr = lane & 15, lg = lane >> 4;

  f32x4 acc[8][4] = {};
  kloop8<CC>(hbuf + ((size_t)(comp * MP + mt * BMX)) * HH,
             W2 + nt * BNX, smem, acc, wr, wc, lr, lg, tid);

  // epilogue: (+b2) * keep, seg-reduce 256 rows by timestamp (LDS reused)
  float* part = (float*)smem;                  // 16*256 floats = 16 KB
  int*   tarr = (int*)((char*)smem + 16384);   // 256 ints
  float* karr = (float*)((char*)smem + 17408); // 256 floats
  if (tid < 256) {
    int mglob = mt * BMX + tid;
    int mi = mglob < LL ? mglob : LL - 1;
    int r2 = ridx[comp * LL + mi];
    tarr[tid] = r2 >> 11;
    karr[tid] = keepf[(comp << 10) + mglob];   // 0 for padded/duplicate rows
  }
  for (int e = tid; e < TT * 256; e += 512) part[e] = 0.0f;
  __syncthreads();
  const float* b2p = b2 + nt * BNX;
#pragma unroll
  for (int i = 0; i < 8; ++i)
#pragma unroll
    for (int j = 0; j < 4; ++j) {
      int nl = wc * 64 + j * 16 + lr;
      float bias = b2p[nl];
#pragma unroll
      for (int rr = 0; rr < 4; ++rr) {
        int ml = wr * 128 + i * 16 + lg * 4 + rr;
        float v = (acc[i][j][rr] + bias) * karr[ml];
        atomicAdd(&part[tarr[ml] * 256 + nl], v);
      }
    }
  __syncthreads();
  float* pout = partial + ((size_t)(comp * MTX + mt)) * TT * CC + nt * BNX;
  for (int e = tid; e < TT * 256; e += 512) {
    int t2 = e >> 8, c = e & 255;
    pout[(size_t)t2 * CC + c] = part[e];
  }
}

// --------------------------- final reduce over m-tiles ---------------------
__global__ void reduce_kernel(const float* __restrict__ partial,
                              float* __restrict__ out) {
  int idx = blockIdx.x * 256 + threadIdx.x;     // = t*32768 + comp*1024 + c
  int c    = idx & (CC - 1);
  int comp = (idx >> 10) & (NCOMP - 1);
  int t    = idx >> 15;
  float s = 0.0f;
#pragma unroll
  for (int mt = 0; mt < MTX; ++mt)
    s += partial[(((size_t)(comp * MTX + mt)) * TT + t) * CC + c];
  out[idx] = s * (1.0f / 4096.0f);
}

// ---------------------------------------------------------------------------
extern "C" void kernel_launch(void* const* d_in, const int* in_sizes, int n_in,
                              void* d_out, int out_size, void* d_ws, size_t ws_size,
                              hipStream_t stream) {
  const float* x    = (const float*)d_in[0];
  const int*   ridx = (const int*)d_in[3];
  const float* nW1  = (const float*)d_in[4];
  const float* nb1  = (const float*)d_in[5];
  const float* nW2  = (const float*)d_in[6];
  const float* nb2  = (const float*)d_in[7];
  const float* eW1  = (const float*)d_in[8];
  const float* eb1  = (const float*)d_in[9];
  const float* eW2  = (const float*)d_in[10];
  const float* eb2  = (const float*)d_in[11];
  float* out = (float*)d_out;

  // ws: [h 134MB][bitmap][keep][partial 8.4MB][Ab 134MB]  ~277 MB
  const size_t H_B   = (size_t)NCOMP * MP * HH * 2;
  const size_t BMP_B = (size_t)NCOMP * 1024 * 4;
  const size_t KP_B  = (size_t)NCOMP * 1024 * 4;
  const size_t PRT_B = (size_t)NCOMP * MTX * TT * CC * 4;
  const size_t base  = H_B + BMP_B + KP_B + PRT_B;

  char* ws = (char*)d_ws;
  short* hbuf      = (short*)ws;
  unsigned* bitmap = (unsigned*)(ws + H_B);
  float* keepf     = (float*)(ws + H_B + BMP_B);
  float* partial   = (float*)(ws + H_B + BMP_B + KP_B);
  short* Ab        = (short*)(ws + base);

  hipMemsetAsync(bitmap, 0, BMP_B, stream);
  dedup_kernel<<<NCOMP, 256, 0, stream>>>(ridx, bitmap, keepf);
  gather_kernel<<<NCOMP * 128, 256, 0, stream>>>(x, ridx, Ab);
  gemm1_kernel<<<NCOMP * MTX * NT1X, 512, 0, stream>>>(nW1, nb1, eW1, eb1, Ab, hbuf);
  gemm2_kernel<<<NCOMP * MTX * NT2X, 512, 0, stream>>>(hbuf, ridx, nW2, nb2, eW2, eb2, keepf, partial);
  reduce_kernel<<<out_size / 256, 256, 0, stream>>>(partial, out);
}

// Round 11
// 919.927 us; speedup vs baseline: 1.3316x; 1.3316x over previous
//
#include <hip/hip_runtime.h>
#include <math.h>

// ---------------------------------------------------------------------------
// Disentangler: 32 component-MLPs over sampled token rows + masked seg-pool.
// Round-11 (= r9 + convergence fixes): 256x128 block / 4 waves of 128x64,
// A dbuf via global_load_lds (pre-swizzled bf16), B fused W-transpose with a
// 3-tile pipeline: bload(u+3)->fp32 regs, cvt(u+2)->bf16 regs, bwrite(u+1)
// pure ds_write (serial segment minimized). part[] stride 257 kills the
// 4-way LDS-atomic bank conflicts in gemm2's seg-reduce. No sched_barrier.
// ---------------------------------------------------------------------------

typedef __attribute__((ext_vector_type(8))) short bf16x8;
typedef __attribute__((ext_vector_type(4))) short s16x4;
typedef __attribute__((ext_vector_type(4))) float f32x4;
typedef unsigned int u32;

constexpr int TT    = 16;
constexpr int TOKN  = 4096;
constexpr int DD    = 2048;
constexpr int HH    = 2048;
constexpr int CC    = 1024;
constexpr int LL    = 1000;
constexpr int NCOMP = 32;
constexpr int MP    = 1024;
constexpr int BMX = 256, BNX = 128;
constexpr int MTX  = MP / BMX;    // 4 m-tiles
constexpr int NT1 = HH / BNX;     // 16 n-tiles (gemm1)
constexpr int NT2 = CC / BNX;     // 8  n-tiles (gemm2)
constexpr int NT  = 2048 / 64;    // 32 K-tiles (K = 2048 both GEMMs)

__device__ __forceinline__ short f2bf(float f) {
  __bf16 h = (__bf16)f;
  return *reinterpret_cast<short*>(&h);
}
// Row swizzle (period 64): data-granule g of a 64-elem chunk lives at slot
// g ^ swz(row). Identical layout in Ab, h, and the LDS tiles.
__device__ __forceinline__ int swz(int row) {
  return (row & 7) ^ ((row >> 3) & 7);
}
__device__ __forceinline__ int sw(int row, int gran) {   // short offset
  return (row << 6) + ((gran ^ swz(row)) << 3);
}
__device__ __forceinline__ void gl_lds16(const void* g, void* l) {
  __builtin_amdgcn_global_load_lds(
      (const __attribute__((address_space(1))) u32*)g,
      (__attribute__((address_space(3))) u32*)l, 16, 0, 0);
}

// --------------------------- dedup ----------------------------------------
__global__ void dedup_kernel(const int* __restrict__ ridx,
                             unsigned* __restrict__ bitmap,
                             float* __restrict__ keepf) {
  int comp = blockIdx.x;
  for (int l = threadIdx.x; l < MP; l += 256) {
    float kv = 0.0f;
    if (l < LL) {
      int r = ridx[comp * LL + l];
      unsigned bit = 1u << (r & 31);
      unsigned old = atomicOr(&bitmap[(comp << 10) + (r >> 5)], bit);
      kv = (old & bit) ? 0.0f : 1.0f;
    }
    keepf[(comp << 10) + l] = kv;
  }
}

// --------------------------- gather: x rows -> pre-swizzled bf16 -----------
__global__ __launch_bounds__(256) void gather_kernel(
    const float* __restrict__ x, const int* __restrict__ ridx,
    short* __restrict__ Ab) {
  int bid = blockIdx.x;
  int comp = bid >> 7, rgrp = bid & 127;
  int t = threadIdx.x;
  int tr = t >> 5, tn = t & 31;
  int m = rgrp * 8 + tr;
  int mi = m < LL ? m : LL - 1;
  int r = ridx[comp * LL + mi];
  int tokoff = comp >= 16 ? TOKN / 2 : 0;
  const float* src = x + ((size_t)(r >> 11) * TOKN + (r & 2047) + tokoff) * DD;
  short* drow = Ab + ((size_t)(comp * MP + m)) * DD;
  int s_m = swz(m);
#pragma unroll
  for (int i = 0; i < 8; ++i) {
    int gi = tn + 32 * i;
    float4 f0 = *reinterpret_cast<const float4*>(src + gi * 8);
    float4 f1 = *reinterpret_cast<const float4*>(src + gi * 8 + 4);
    bf16x8 pk;
    pk[0]=f2bf(f0.x); pk[1]=f2bf(f0.y); pk[2]=f2bf(f0.z); pk[3]=f2bf(f0.w);
    pk[4]=f2bf(f1.x); pk[5]=f2bf(f1.y); pk[6]=f2bf(f1.z); pk[7]=f2bf(f1.w);
    int c = gi >> 3, g = gi & 7;
    *reinterpret_cast<bf16x8*>(&drow[c * 64 + ((g ^ s_m) << 3)]) = pk;
  }
}

// --------------------------- shared K-loop ---------------------------------
// LDS (shorts): Abuf[2][16384] @0 (256 rows x 64k), Bbuf[8192] @32768.
// Iter u: gate vmcnt(16|8|0); compute(u); barrier; bwrite B(u+1) [pure ds,
// from bb16 regs]; lgkm(0); barrier; cvt B(u+2) [br->bb16, compiler vmcnt(8)];
// bload(u+3)->br; aglds(u+2)->Abuf[u&1].
// Ledger (steady): outstanding at gate = [aglds(u):8, bload(u+2):8,
// aglds(u+1):8] -> vmcnt(16) drains aglds(u). Tail: gate(NT-2)=vmcnt(8),
// gate(NT-1)=vmcnt(0).
template<int LDW>
__device__ __forceinline__ void kloop(
    const short* __restrict__ aBase,   // bf16 pre-swizzled rows, stride 2048
    const float* __restrict__ wBase,   // fp32 W [k][LDW] at col offset nt*BNX
    short* sm, f32x4 (&acc)[8][4],
    int wm, int wn, int lr, int lg, int tid) {
  const short* aSrc0 = aBase + (size_t)(tid >> 3) * 2048 + (tid & 7) * 8;
  int ldsA0 = tid * 8;
  int tn = tid & 31, tkb = tid >> 5, bn0 = tn * 4;
  const float* wCol = wBase + bn0;

  float4  br[8];     // fp32 W rows (tile u+3)
  bf16x8  bb[4];     // cvt'd bf16 columns (tile u+2 -> bwrite next iter)

  auto aglds = [&](int t, int buf) {
    short* l = sm + buf * 16384;
#pragma unroll
    for (int q = 0; q < 8; ++q)
      gl_lds16(aSrc0 + (size_t)q * 65536 + t * 64, l + ldsA0 + q * 2048);
  };
  auto bload = [&](int t) {
    const float* bb_ = wCol + (size_t)(t * 64 + tkb * 8) * LDW;
#pragma unroll
    for (int i = 0; i < 8; ++i)
      br[i] = *reinterpret_cast<const float4*>(bb_ + (size_t)i * LDW);
  };
  auto bcvt = [&]() {
#pragma unroll
    for (int j = 0; j < 4; ++j) {
      bf16x8 pk;
#pragma unroll
      for (int i = 0; i < 8; ++i) pk[i] = f2bf((&br[i].x)[j]);
      bb[j] = pk;
    }
  };
  auto bwrite = [&]() {
    short* Bs = sm + 32768;
#pragma unroll
    for (int j = 0; j < 4; ++j)
      *reinterpret_cast<bf16x8*>(&Bs[sw(bn0 + j, tkb)]) = bb[j];
  };
  auto compute = [&](int d) {
    const short* A = sm + d * 16384;
    const short* B = sm + 32768;
#pragma unroll
    for (int kk = 0; kk < 2; ++kk) {
      bf16x8 af[8], bfr[4];
#pragma unroll
      for (int i = 0; i < 8; ++i)
        af[i] = *reinterpret_cast<const bf16x8*>(&A[sw(wm + i * 16 + lr, kk * 4 + lg)]);
#pragma unroll
      for (int j = 0; j < 4; ++j)
        bfr[j] = *reinterpret_cast<const bf16x8*>(&B[sw(wn + j * 16 + lr, kk * 4 + lg)]);
      __builtin_amdgcn_s_setprio(1);
#pragma unroll
      for (int i = 0; i < 8; ++i)
#pragma unroll
        for (int j = 0; j < 4; ++j)
          acc[i][j] = __builtin_amdgcn_mfma_f32_16x16x32_bf16(af[i], bfr[j], acc[i][j], 0, 0, 0);
      __builtin_amdgcn_s_setprio(0);
    }
  };

  // prologue: B(0)->LDS (via br->bb), A(0) glds, bb=B(1), br=B(2), A(1) glds.
  bload(0);
  bcvt();                 // waits bload(0); bb = B(0)
  bwrite();               // B(0) -> Bbuf
  aglds(0, 0);
  bload(1);
  bcvt();                 // waits bload(1) (drains aglds(0) too); bb = B(1)
  bload(2);
  aglds(1, 1);
  asm volatile("s_waitcnt lgkmcnt(0)" ::: "memory");
  __builtin_amdgcn_s_barrier();

#pragma unroll 1
  for (int u = 0; u < NT; ++u) {
    if (u < NT - 2) {
      asm volatile("s_waitcnt vmcnt(16)" ::: "memory");  // A(u) landed
    } else if (u == NT - 2) {
      asm volatile("s_waitcnt vmcnt(8)" ::: "memory");
    } else {
      asm volatile("s_waitcnt vmcnt(0)" ::: "memory");
    }
    compute(u & 1);
    __builtin_amdgcn_s_barrier();          // all waves done reading A(u), B(u)
    if (u + 1 < NT) {
      bwrite();                            // B(u+1) -> Bbuf, pure ds_write
      asm volatile("s_waitcnt lgkmcnt(0)" ::: "memory");
    }
    __builtin_amdgcn_s_barrier();
    if (u + 2 < NT) {
      bcvt();                              // bb = B(u+2); compiler vmcnt(8)
      if (u + 3 < NT) bload(u + 3);
      aglds(u + 2, u & 1);
    }
  }
}

// --------------------------- GEMM1: h = gelu(x_sel @ W1 + b1) --------------
__global__ __launch_bounds__(256, 2) void gemm1_kernel(
    const float* __restrict__ nW1, const float* __restrict__ nb1,
    const float* __restrict__ eW1, const float* __restrict__ eb1,
    const short* __restrict__ Ab, short* __restrict__ hbuf) {
  __shared__ short smem[40960];   // 80 KB

  constexpr int NWG = NCOMP * MTX * NT1;   // 2048
  constexpr int CPX = NWG / 8;
  int b0 = blockIdx.x;
  int lb = (b0 & 7) * CPX + (b0 >> 3);     // XCD-chunked (T1), bijective
  int comp = lb / (MTX * NT1);
  int rem  = lb % (MTX * NT1);
  int mt = rem / NT1, nt = rem % NT1;
  bool isEdge = comp >= 16;
  int k16 = isEdge ? comp - 16 : comp;
  const float* W1 = (isEdge ? eW1 : nW1) + (size_t)k16 * DD * HH;
  const float* b1 = (isEdge ? eb1 : nb1) + (size_t)k16 * HH;

  int tid = threadIdx.x, lane = tid & 63, wid = tid >> 6;
  int wm = (wid >> 1) << 7, wn = (wid & 1) << 6;   // 2x2 waves of 128x64
  int lr = lane & 15, lg = lane >> 4;

  f32x4 acc[8][4] = {};
  kloop<HH>(Ab + ((size_t)(comp * MP + mt * BMX)) * DD,
            W1 + nt * BNX, smem, acc, wm, wn, lr, lg, tid);

  // epilogue: +b1, exact gelu -> Cs (stride 132), then coalesced
  // PRE-SWIZZLED bf16 h store (so gemm2 can global_load_lds it)
  __builtin_amdgcn_s_barrier();
  short* Cs = smem;                        // 256*132 = 33792 shorts
  const float* b1p = b1 + nt * BNX;
#pragma unroll
  for (int i = 0; i < 8; ++i)
#pragma unroll
    for (int j = 0; j < 4; ++j) {
      int nl = wn + j * 16 + lr;
      float bias = b1p[nl];
#pragma unroll
      for (int rr = 0; rr < 4; ++rr) {
        int ml = wm + i * 16 + lg * 4 + rr;
        float v = acc[i][j][rr] + bias;
        float ge = 0.5f * v * (1.0f + erff(v * 0.70710678118654752f));
        Cs[ml * 132 + nl] = f2bf(ge);
      }
    }
  __syncthreads();
  short* hrow = hbuf + ((size_t)(comp * MP + mt * BMX)) * HH;
#pragma unroll
  for (int q = 0; q < 32; ++q) {
    int gl = q * 256 + tid;
    int r = gl >> 5, gg = gl & 31;         // 32 4-short granules per row
    s16x4 v = *reinterpret_cast<const s16x4*>(&Cs[r * 132 + gg * 4]);
    int dst = (nt * 2 + (gg >> 4)) * 64 + ((((gg >> 1) & 7) ^ swz(r)) << 3) + (gg & 1) * 4;
    *reinterpret_cast<s16x4*>(&hrow[(size_t)r * HH + dst]) = v;
  }
}

// --------------------------- GEMM2: o = h @ W2 + b2, masked seg-reduce -----
__global__ __launch_bounds__(256, 2) void gemm2_kernel(
    const short* __restrict__ hbuf, const int* __restrict__ ridx,
    const float* __restrict__ nW2, const float* __restrict__ nb2,
    const float* __restrict__ eW2, const float* __restrict__ eb2,
    const float* __restrict__ keepf, float* __restrict__ partial) {
  __shared__ short smem[40960];

  constexpr int NWG = NCOMP * MTX * NT2;   // 1024
  constexpr int CPX = NWG / 8;
  int b0 = blockIdx.x;
  int lb = (b0 & 7) * CPX + (b0 >> 3);
  int comp = lb / (MTX * NT2);
  int rem  = lb % (MTX * NT2);
  int mt = rem / NT2, nt = rem % NT2;
  bool isEdge = comp >= 16;
  int k16 = isEdge ? comp - 16 : comp;
  const float* W2 = (isEdge ? eW2 : nW2) + (size_t)k16 * HH * CC;
  const float* b2 = (isEdge ? eb2 : nb2) + (size_t)k16 * CC;

  int tid = threadIdx.x, lane = tid & 63, wid = tid >> 6;
  int wm = (wid >> 1) << 7, wn = (wid & 1) << 6;
  int lr = lane & 15, lg = lane >> 4;

  f32x4 acc[8][4] = {};
  kloop<CC>(hbuf + ((size_t)(comp * MP + mt * BMX)) * HH,
            W2 + nt * BNX, smem, acc, wm, wn, lr, lg, tid);

  // epilogue: (+b2) * keep, seg-reduce 256 rows by timestamp.
  // part stride 257 (257%32==1) spreads the t-dimension across banks ->
  // kills the 4-way same-bank conflicts of the old stride-256 layout.
  __builtin_amdgcn_s_barrier();
  float* part = (float*)smem;                     // 16*257 floats = 16.4 KB
  int*   tarr = (int*)((char*)smem + 16640);      // 256 ints
  float* karr = (float*)((char*)smem + 17664);    // 256 floats
  if (tid < BMX) {
    int mglob = mt * BMX + tid;
    int mi = mglob < LL ? mglob : LL - 1;
    int r2 = ridx[comp * LL + mi];
    tarr[tid] = r2 >> 11;
    karr[tid] = keepf[(comp << 10) + mglob];      // 0 for padded/dup rows
  }
  for (int e = tid; e < TT * 257; e += 256) part[e] = 0.0f;
  __syncthreads();
  const float* b2p = b2 + nt * BNX;
#pragma unroll
  for (int i = 0; i < 8; ++i)
#pragma unroll
    for (int j = 0; j < 4; ++j) {
      int nl = wn + j * 16 + lr;
      float bias = b2p[nl];
#pragma unroll
      for (int rr = 0; rr < 4; ++rr) {
        int ml = wm + i * 16 + lg * 4 + rr;
        float v = (acc[i][j][rr] + bias) * karr[ml];
        atomicAdd(&part[tarr[ml] * 257 + nl], v);
      }
    }
  __syncthreads();
  float* pout = partial + ((size_t)(comp * MTX + mt)) * TT * CC + nt * BNX;
  for (int e = tid; e < TT * BNX; e += 256) {
    int t2 = e >> 7, c = e & 127;
    pout[(size_t)t2 * CC + c] = part[t2 * 257 + c];
  }
}

// --------------------------- final reduce over m-tiles ---------------------
__global__ void reduce_kernel(const float* __restrict__ partial,
                              float* __restrict__ out) {
  int idx = blockIdx.x * 256 + threadIdx.x;
  int c    = idx & (CC - 1);
  int comp = (idx >> 10) & (NCOMP - 1);
  int t    = idx >> 15;
  float s = 0.0f;
#pragma unroll
  for (int mt = 0; mt < MTX; ++mt)
    s += partial[(((size_t)(comp * MTX + mt)) * TT + t) * CC + c];
  out[idx] = s * (1.0f / 4096.0f);
}

// ---------------------------------------------------------------------------
extern "C" void kernel_launch(void* const* d_in, const int* in_sizes, int n_in,
                              void* d_out, int out_size, void* d_ws, size_t ws_size,
                              hipStream_t stream) {
  const float* x    = (const float*)d_in[0];
  const int*   ridx = (const int*)d_in[3];
  const float* nW1  = (const float*)d_in[4];
  const float* nb1  = (const float*)d_in[5];
  const float* nW2  = (const float*)d_in[6];
  const float* nb2  = (const float*)d_in[7];
  const float* eW1  = (const float*)d_in[8];
  const float* eb1  = (const float*)d_in[9];
  const float* eW2  = (const float*)d_in[10];
  const float* eb2  = (const float*)d_in[11];
  float* out = (float*)d_out;

  // ws: [h 134MB][bitmap][keep][partial 8.4MB][Ab 134MB]  ~277 MB
  const size_t H_B   = (size_t)NCOMP * MP * HH * 2;
  const size_t BMP_B = (size_t)NCOMP * 1024 * 4;
  const size_t KP_B  = (size_t)NCOMP * 1024 * 4;
  const size_t PRT_B = (size_t)NCOMP * MTX * TT * CC * 4;
  const size_t base  = H_B + BMP_B + KP_B + PRT_B;

  char* ws = (char*)d_ws;
  short* hbuf      = (short*)ws;
  unsigned* bitmap = (unsigned*)(ws + H_B);
  float* keepf     = (float*)(ws + H_B + BMP_B);
  float* partial   = (float*)(ws + H_B + BMP_B + KP_B);
  short* Ab        = (short*)(ws + base);

  hipMemsetAsync(bitmap, 0, BMP_B, stream);
  dedup_kernel<<<NCOMP, 256, 0, stream>>>(ridx, bitmap, keepf);
  gather_kernel<<<NCOMP * 128, 256, 0, stream>>>(x, ridx, Ab);
  gemm1_kernel<<<NCOMP * MTX * NT1, 256, 0, stream>>>(nW1, nb1, eW1, eb1, Ab, hbuf);
  gemm2_kernel<<<NCOMP * MTX * NT2, 256, 0, stream>>>(hbuf, ridx, nW2, nb2, eW2, eb2, keepf, partial);
  reduce_kernel<<<out_size / 256, 256, 0, stream>>>(partial, out);
}

// Round 12
// 806.344 us; speedup vs baseline: 1.5191x; 1.1409x over previous
//
#include <hip/hip_runtime.h>
#include <math.h>

// ---------------------------------------------------------------------------
// Disentangler: 32 component-MLPs over sampled token rows + masked seg-pool.
// Round-12 (= r9 exact + stride-257 gemm2 seg-reduce): 256x128 block / 4
// waves of 128x64, A dbuf via global_load_lds (pre-swizzled bf16), B fused
// W-transpose (fp32 row loads -> reg cvt -> swizzled ds_write) single-buffer,
// 80 KB LDS -> 2 blocks/CU, counted-vmcnt pipeline. r9 kloop untouched.
// ---------------------------------------------------------------------------

typedef __attribute__((ext_vector_type(8))) short bf16x8;
typedef __attribute__((ext_vector_type(4))) short s16x4;
typedef __attribute__((ext_vector_type(4))) float f32x4;
typedef unsigned int u32;

constexpr int TT    = 16;
constexpr int TOKN  = 4096;
constexpr int DD    = 2048;
constexpr int HH    = 2048;
constexpr int CC    = 1024;
constexpr int LL    = 1000;
constexpr int NCOMP = 32;
constexpr int MP    = 1024;
constexpr int BMX = 256, BNX = 128;
constexpr int MTX  = MP / BMX;    // 4 m-tiles
constexpr int NT1 = HH / BNX;     // 16 n-tiles (gemm1)
constexpr int NT2 = CC / BNX;     // 8  n-tiles (gemm2)
constexpr int NT  = 2048 / 64;    // 32 K-tiles (K = 2048 both GEMMs)

__device__ __forceinline__ short f2bf(float f) {
  __bf16 h = (__bf16)f;
  return *reinterpret_cast<short*>(&h);
}
// Row swizzle (period 64): data-granule g of a 64-elem chunk lives at slot
// g ^ swz(row). Identical layout in Ab, h, and the LDS tiles.
__device__ __forceinline__ int swz(int row) {
  return (row & 7) ^ ((row >> 3) & 7);
}
__device__ __forceinline__ int sw(int row, int gran) {   // short offset
  return (row << 6) + ((gran ^ swz(row)) << 3);
}
__device__ __forceinline__ void gl_lds16(const void* g, void* l) {
  __builtin_amdgcn_global_load_lds(
      (const __attribute__((address_space(1))) u32*)g,
      (__attribute__((address_space(3))) u32*)l, 16, 0, 0);
}

// --------------------------- dedup ----------------------------------------
__global__ void dedup_kernel(const int* __restrict__ ridx,
                             unsigned* __restrict__ bitmap,
                             float* __restrict__ keepf) {
  int comp = blockIdx.x;
  for (int l = threadIdx.x; l < MP; l += 256) {
    float kv = 0.0f;
    if (l < LL) {
      int r = ridx[comp * LL + l];
      unsigned bit = 1u << (r & 31);
      unsigned old = atomicOr(&bitmap[(comp << 10) + (r >> 5)], bit);
      kv = (old & bit) ? 0.0f : 1.0f;
    }
    keepf[(comp << 10) + l] = kv;
  }
}

// --------------------------- gather: x rows -> pre-swizzled bf16 -----------
__global__ __launch_bounds__(256) void gather_kernel(
    const float* __restrict__ x, const int* __restrict__ ridx,
    short* __restrict__ Ab) {
  int bid = blockIdx.x;
  int comp = bid >> 7, rgrp = bid & 127;
  int t = threadIdx.x;
  int tr = t >> 5, tn = t & 31;
  int m = rgrp * 8 + tr;
  int mi = m < LL ? m : LL - 1;
  int r = ridx[comp * LL + mi];
  int tokoff = comp >= 16 ? TOKN / 2 : 0;
  const float* src = x + ((size_t)(r >> 11) * TOKN + (r & 2047) + tokoff) * DD;
  short* drow = Ab + ((size_t)(comp * MP + m)) * DD;
  int s_m = swz(m);
#pragma unroll
  for (int i = 0; i < 8; ++i) {
    int gi = tn + 32 * i;
    float4 f0 = *reinterpret_cast<const float4*>(src + gi * 8);
    float4 f1 = *reinterpret_cast<const float4*>(src + gi * 8 + 4);
    bf16x8 pk;
    pk[0]=f2bf(f0.x); pk[1]=f2bf(f0.y); pk[2]=f2bf(f0.z); pk[3]=f2bf(f0.w);
    pk[4]=f2bf(f1.x); pk[5]=f2bf(f1.y); pk[6]=f2bf(f1.z); pk[7]=f2bf(f1.w);
    int c = gi >> 3, g = gi & 7;
    *reinterpret_cast<bf16x8*>(&drow[c * 64 + ((g ^ s_m) << 3)]) = pk;
  }
}

// --------------------------- shared K-loop (r9, unchanged) -----------------
// LDS (shorts): Abuf[2][16384] @0 (256 rows x 64k), Bbuf[8192] @32768.
// Steady-state tile t: gate vmcnt(16) (A(t) oldest beyond bB(t+1)+A(t+1)),
// compute, barrier, bwrite(t+1), bload(t+2), aglds(t+2), lgkm(0), barrier.
template<int LDW>
__device__ __forceinline__ void kloop(
    const short* __restrict__ aBase,   // bf16 pre-swizzled rows, stride 2048
    const float* __restrict__ wBase,   // fp32 W [k][LDW] at col offset nt*BNX
    short* sm, f32x4 (&acc)[8][4],
    int wm, int wn, int lr, int lg, int tid) {
  const short* aSrc0 = aBase + (size_t)(tid >> 3) * 2048 + (tid & 7) * 8;
  int ldsA0 = tid * 8;
  int tn = tid & 31, tkb = tid >> 5, bn0 = tn * 4;
  const float* wCol = wBase + bn0;

  float4 brB[8];

  auto aglds = [&](int t, int buf) {
    short* l = sm + buf * 16384;
#pragma unroll
    for (int q = 0; q < 8; ++q)
      gl_lds16(aSrc0 + (size_t)q * 65536 + t * 64, l + ldsA0 + q * 2048);
  };
  auto bload = [&](int t) {
    const float* bb = wCol + (size_t)(t * 64 + tkb * 8) * LDW;
#pragma unroll
    for (int i = 0; i < 8; ++i)
      brB[i] = *reinterpret_cast<const float4*>(bb + (size_t)i * LDW);
  };
  auto bwrite = [&]() {
    short* Bs = sm + 32768;
#pragma unroll
    for (int j = 0; j < 4; ++j) {
      bf16x8 pk;
#pragma unroll
      for (int i = 0; i < 8; ++i) pk[i] = f2bf((&brB[i].x)[j]);
      *reinterpret_cast<bf16x8*>(&Bs[sw(bn0 + j, tkb)]) = pk;
    }
  };
  auto compute = [&](int d) {
    const short* A = sm + d * 16384;
    const short* B = sm + 32768;
#pragma unroll
    for (int kk = 0; kk < 2; ++kk) {
      bf16x8 af[8], bfr[4];
#pragma unroll
      for (int i = 0; i < 8; ++i)
        af[i] = *reinterpret_cast<const bf16x8*>(&A[sw(wm + i * 16 + lr, kk * 4 + lg)]);
#pragma unroll
      for (int j = 0; j < 4; ++j)
        bfr[j] = *reinterpret_cast<const bf16x8*>(&B[sw(wn + j * 16 + lr, kk * 4 + lg)]);
      __builtin_amdgcn_s_setprio(1);
#pragma unroll
      for (int i = 0; i < 8; ++i)
#pragma unroll
        for (int j = 0; j < 4; ++j)
          acc[i][j] = __builtin_amdgcn_mfma_f32_16x16x32_bf16(af[i], bfr[j], acc[i][j], 0, 0, 0);
      __builtin_amdgcn_s_setprio(0);
    }
  };

  // prologue: bB(0) regs; A(0) glds; write B(0) (compiler waits bB(0) only,
  // vmcnt(8) -> A(0) stays in flight); bB(1); A(1) glds.
  bload(0);
  aglds(0, 0);
  bwrite();
  bload(1);
  aglds(1, 1);
  asm volatile("s_waitcnt lgkmcnt(0)" ::: "memory");
  __builtin_amdgcn_s_barrier();

#pragma unroll 1
  for (int t = 0; t < NT; ++t) {
    if (t < NT - 1) {
      asm volatile("s_waitcnt vmcnt(16)" ::: "memory");  // A(t) landed
    } else {
      asm volatile("s_waitcnt vmcnt(0)" ::: "memory");
    }
    __builtin_amdgcn_sched_barrier(0);
    compute(t & 1);
    __builtin_amdgcn_s_barrier();          // all waves done reading A(t), B(t)
    if (t + 1 < NT) {
      bwrite();                            // B(t+1) -> Bbuf (vmcnt(8) auto)
      if (t + 2 < NT) {
        bload(t + 2);                      // issued BEFORE aglds (ordering!)
        aglds(t + 2, t & 1);
      }
      asm volatile("s_waitcnt lgkmcnt(0)" ::: "memory");
      __builtin_amdgcn_s_barrier();
    }
  }
}

// --------------------------- GEMM1: h = gelu(x_sel @ W1 + b1) --------------
__global__ __launch_bounds__(256, 2) void gemm1_kernel(
    const float* __restrict__ nW1, const float* __restrict__ nb1,
    const float* __restrict__ eW1, const float* __restrict__ eb1,
    const short* __restrict__ Ab, short* __restrict__ hbuf) {
  __shared__ short smem[40960];   // 80 KB

  constexpr int NWG = NCOMP * MTX * NT1;   // 2048
  constexpr int CPX = NWG / 8;
  int b0 = blockIdx.x;
  int lb = (b0 & 7) * CPX + (b0 >> 3);     // XCD-chunked (T1), bijective
  int comp = lb / (MTX * NT1);
  int rem  = lb % (MTX * NT1);
  int mt = rem / NT1, nt = rem % NT1;
  bool isEdge = comp >= 16;
  int k16 = isEdge ? comp - 16 : comp;
  const float* W1 = (isEdge ? eW1 : nW1) + (size_t)k16 * DD * HH;
  const float* b1 = (isEdge ? eb1 : nb1) + (size_t)k16 * HH;

  int tid = threadIdx.x, lane = tid & 63, wid = tid >> 6;
  int wm = (wid >> 1) << 7, wn = (wid & 1) << 6;   // 2x2 waves of 128x64
  int lr = lane & 15, lg = lane >> 4;

  f32x4 acc[8][4] = {};
  kloop<HH>(Ab + ((size_t)(comp * MP + mt * BMX)) * DD,
            W1 + nt * BNX, smem, acc, wm, wn, lr, lg, tid);

  // epilogue: +b1, exact gelu -> Cs (stride 132), then coalesced
  // PRE-SWIZZLED bf16 h store (so gemm2 can global_load_lds it)
  __builtin_amdgcn_s_barrier();
  short* Cs = smem;                        // 256*132 = 33792 shorts
  const float* b1p = b1 + nt * BNX;
#pragma unroll
  for (int i = 0; i < 8; ++i)
#pragma unroll
    for (int j = 0; j < 4; ++j) {
      int nl = wn + j * 16 + lr;
      float bias = b1p[nl];
#pragma unroll
      for (int rr = 0; rr < 4; ++rr) {
        int ml = wm + i * 16 + lg * 4 + rr;
        float v = acc[i][j][rr] + bias;
        float ge = 0.5f * v * (1.0f + erff(v * 0.70710678118654752f));
        Cs[ml * 132 + nl] = f2bf(ge);
      }
    }
  __syncthreads();
  short* hrow = hbuf + ((size_t)(comp * MP + mt * BMX)) * HH;
#pragma unroll
  for (int q = 0; q < 32; ++q) {
    int gl = q * 256 + tid;
    int r = gl >> 5, gg = gl & 31;         // 32 4-short granules per row
    s16x4 v = *reinterpret_cast<const s16x4*>(&Cs[r * 132 + gg * 4]);
    int dst = (nt * 2 + (gg >> 4)) * 64 + ((((gg >> 1) & 7) ^ swz(r)) << 3) + (gg & 1) * 4;
    *reinterpret_cast<s16x4*>(&hrow[(size_t)r * HH + dst]) = v;
  }
}

// --------------------------- GEMM2: o = h @ W2 + b2, masked seg-reduce -----
__global__ __launch_bounds__(256, 2) void gemm2_kernel(
    const short* __restrict__ hbuf, const int* __restrict__ ridx,
    const float* __restrict__ nW2, const float* __restrict__ nb2,
    const float* __restrict__ eW2, const float* __restrict__ eb2,
    const float* __restrict__ keepf, float* __restrict__ partial) {
  __shared__ short smem[40960];

  constexpr int NWG = NCOMP * MTX * NT2;   // 1024
  constexpr int CPX = NWG / 8;
  int b0 = blockIdx.x;
  int lb = (b0 & 7) * CPX + (b0 >> 3);
  int comp = lb / (MTX * NT2);
  int rem  = lb % (MTX * NT2);
  int mt = rem / NT2, nt = rem % NT2;
  bool isEdge = comp >= 16;
  int k16 = isEdge ? comp - 16 : comp;
  const float* W2 = (isEdge ? eW2 : nW2) + (size_t)k16 * HH * CC;
  const float* b2 = (isEdge ? eb2 : nb2) + (size_t)k16 * CC;

  int tid = threadIdx.x, lane = tid & 63, wid = tid >> 6;
  int wm = (wid >> 1) << 7, wn = (wid & 1) << 6;
  int lr = lane & 15, lg = lane >> 4;

  f32x4 acc[8][4] = {};
  kloop<CC>(hbuf + ((size_t)(comp * MP + mt * BMX)) * HH,
            W2 + nt * BNX, smem, acc, wm, wn, lr, lg, tid);

  // epilogue: (+b2) * keep, seg-reduce 256 rows by timestamp.
  // part stride 257 (257%32==1): the t dimension now spreads across banks,
  // killing the deterministic 4-way same-bank atomicAdd collisions of the
  // old stride-256 layout (4 lanes/bank-quad share nl%32).
  __builtin_amdgcn_s_barrier();
  float* part = (float*)smem;                     // 16*257 floats
  int*   tarr = (int*)((char*)smem + 16640);      // 256 ints
  float* karr = (float*)((char*)smem + 17664);    // 256 floats
  if (tid < BMX) {
    int mglob = mt * BMX + tid;
    int mi = mglob < LL ? mglob : LL - 1;
    int r2 = ridx[comp * LL + mi];
    tarr[tid] = r2 >> 11;
    karr[tid] = keepf[(comp << 10) + mglob];      // 0 for padded/dup rows
  }
  for (int e = tid; e < TT * 257; e += 256) part[e] = 0.0f;
  __syncthreads();
  const float* b2p = b2 + nt * BNX;
#pragma unroll
  for (int i = 0; i < 8; ++i)
#pragma unroll
    for (int j = 0; j < 4; ++j) {
      int nl = wn + j * 16 + lr;
      float bias = b2p[nl];
#pragma unroll
      for (int rr = 0; rr < 4; ++rr) {
        int ml = wm + i * 16 + lg * 4 + rr;
        float v = (acc[i][j][rr] + bias) * karr[ml];
        atomicAdd(&part[tarr[ml] * 257 + nl], v);
      }
    }
  __syncthreads();
  float* pout = partial + ((size_t)(comp * MTX + mt)) * TT * CC + nt * BNX;
  for (int e = tid; e < TT * BNX; e += 256) {
    int t2 = e >> 7, c = e & 127;
    pout[(size_t)t2 * CC + c] = part[t2 * 257 + c];
  }
}

// --------------------------- final reduce over m-tiles ---------------------
__global__ void reduce_kernel(const float* __restrict__ partial,
                              float* __restrict__ out) {
  int idx = blockIdx.x * 256 + threadIdx.x;
  int c    = idx & (CC - 1);
  int comp = (idx >> 10) & (NCOMP - 1);
  int t    = idx >> 15;
  float s = 0.0f;
#pragma unroll
  for (int mt = 0; mt < MTX; ++mt)
    s += partial[(((size_t)(comp * MTX + mt)) * TT + t) * CC + c];
  out[idx] = s * (1.0f / 4096.0f);
}

// ---------------------------------------------------------------------------
extern "C" void kernel_launch(void* const* d_in, const int* in_sizes, int n_in,
                              void* d_out, int out_size, void* d_ws, size_t ws_size,
                              hipStream_t stream) {
  const float* x    = (const float*)d_in[0];
  const int*   ridx = (const int*)d_in[3];
  const float* nW1  = (const float*)d_in[4];
  const float* nb1  = (const float*)d_in[5];
  const float* nW2  = (const float*)d_in[6];
  const float* nb2  = (const float*)d_in[7];
  const float* eW1  = (const float*)d_in[8];
  const float* eb1  = (const float*)d_in[9];
  const float* eW2  = (const float*)d_in[10];
  const float* eb2  = (const float*)d_in[11];
  float* out = (float*)d_out;

  // ws: [h 134MB][bitmap][keep][partial 8.4MB][Ab 134MB]  ~277 MB
  const size_t H_B   = (size_t)NCOMP * MP * HH * 2;
  const size_t BMP_B = (size_t)NCOMP * 1024 * 4;
  const size_t KP_B  = (size_t)NCOMP * 1024 * 4;
  const size_t PRT_B = (size_t)NCOMP * MTX * TT * CC * 4;
  const size_t base  = H_B + BMP_B + KP_B + PRT_B;

  char* ws = (char*)d_ws;
  short* hbuf      = (short*)ws;
  unsigned* bitmap = (unsigned*)(ws + H_B);
  float* keepf     = (float*)(ws + H_B + BMP_B);
  float* partial   = (float*)(ws + H_B + BMP_B + KP_B);
  short* Ab        = (short*)(ws + base);

  hipMemsetAsync(bitmap, 0, BMP_B, stream);
  dedup_kernel<<<NCOMP, 256, 0, stream>>>(ridx, bitmap, keepf);
  gather_kernel<<<NCOMP * 128, 256, 0, stream>>>(x, ridx, Ab);
  gemm1_kernel<<<NCOMP * MTX * NT1, 256, 0, stream>>>(nW1, nb1, eW1, eb1, Ab, hbuf);
  gemm2_kernel<<<NCOMP * MTX * NT2, 256, 0, stream>>>(hbuf, ridx, nW2, nb2, eW2, eb2, keepf, partial);
  reduce_kernel<<<out_size / 256, 256, 0, stream>>>(partial, out);
}